// Round 1
// baseline (1953.597 us; speedup 1.0000x reference)
//
#include <hip/hip_runtime.h>
#include <math.h>

#define B_  16
#define N_  1024
#define L_  7
#define D_  512
#define H_  8
#define HD_ 64
#define BN_ (B_ * N_)

// ---------------------------------------------------------------------------
// Kernel 0: lag softmax + weighted aggregation over L=7 lags.
// lagged_agg[b,n,d] = sum_l softmax(lag_w)[l] * lagged[b,n,l,d]
// Memory-bound: 240 MB read, 34 MB write.
// ---------------------------------------------------------------------------
__global__ __launch_bounds__(256)
void lag_agg_kernel(const float* __restrict__ lf, const float* __restrict__ lw,
                    float* __restrict__ out) {
  const int i = blockIdx.x * 256 + threadIdx.x;   // float4 index over BN_*D_/4
  float w[L_];
  float m = -INFINITY;
#pragma unroll
  for (int l = 0; l < L_; ++l) { w[l] = lw[l]; m = fmaxf(m, w[l]); }
  float s = 0.f;
#pragma unroll
  for (int l = 0; l < L_; ++l) { w[l] = __expf(w[l] - m); s += w[l]; }
  const float inv = 1.f / s;

  const int d4 = i & (D_ / 4 - 1);
  const int bn = i >> 7;                          // i / (D_/4)
  const float4* src = (const float4*)lf + (size_t)bn * (L_ * D_ / 4) + d4;
  float4 acc = make_float4(0.f, 0.f, 0.f, 0.f);
#pragma unroll
  for (int l = 0; l < L_; ++l) {
    const float4 v = src[(size_t)l * (D_ / 4)];
    const float wl = w[l] * inv;
    acc.x += v.x * wl; acc.y += v.y * wl; acc.z += v.z * wl; acc.w += v.w * wl;
  }
  ((float4*)out)[i] = acc;
}

// ---------------------------------------------------------------------------
// Kernel 1: C[M,512] = X[M,512] @ W[512,512]^T + bias   (torch Linear)
// Tiled f32 GEMM: 64x64 tile, BK=16, 256 threads, 4x4 micro-tile.
// LDS stride 68 keeps float4 alignment (272 B rows) and <=2-way conflicts.
// ---------------------------------------------------------------------------
__global__ __launch_bounds__(256)
void gemm_xwt_kernel(const float* __restrict__ X, const float* __restrict__ W,
                     const float* __restrict__ bias, float* __restrict__ C) {
  __shared__ __align__(16) float As[16][68];
  __shared__ __align__(16) float Bs[16][68];
  const int t  = threadIdx.x;
  const int tx = t & 15, ty = t >> 4;
  const int m0 = blockIdx.y << 6;
  const int n0 = blockIdx.x << 6;
  const int lr = t >> 2;            // 0..63 row within tile
  const int lk = (t & 3) << 2;      // k offset {0,4,8,12}
  const float* xp = X + (size_t)(m0 + lr) * D_ + lk;
  const float* wp = W + (size_t)(n0 + lr) * D_ + lk;

  float c[4][4] = {};
  for (int k0 = 0; k0 < D_; k0 += 16) {
    const float4 av = *(const float4*)(xp + k0);
    const float4 bv = *(const float4*)(wp + k0);
    __syncthreads();                 // previous inner-loop LDS reads done
    As[lk + 0][lr] = av.x; As[lk + 1][lr] = av.y;
    As[lk + 2][lr] = av.z; As[lk + 3][lr] = av.w;
    Bs[lk + 0][lr] = bv.x; Bs[lk + 1][lr] = bv.y;
    Bs[lk + 2][lr] = bv.z; Bs[lk + 3][lr] = bv.w;
    __syncthreads();
#pragma unroll
    for (int k = 0; k < 16; ++k) {
      const float4 a = *(const float4*)(&As[k][ty << 2]);
      const float4 b = *(const float4*)(&Bs[k][tx << 2]);
      const float a_[4] = {a.x, a.y, a.z, a.w};
      const float b_[4] = {b.x, b.y, b.z, b.w};
#pragma unroll
      for (int i = 0; i < 4; ++i)
#pragma unroll
        for (int j = 0; j < 4; ++j) c[i][j] += a_[i] * b_[j];
    }
  }
#pragma unroll
  for (int i = 0; i < 4; ++i) {
    const int row = m0 + (ty << 2) + i;
    const int col = n0 + (tx << 2);
    const float4 bv = *(const float4*)(bias + col);
    float4 o;
    o.x = c[i][0] + bv.x; o.y = c[i][1] + bv.y;
    o.z = c[i][2] + bv.z; o.w = c[i][3] + bv.w;
    *(float4*)(C + (size_t)row * D_ + col) = o;
  }
}

// ---------------------------------------------------------------------------
// Kernel 2: flash-style attention per (b,h). 64 Q-rows per block, online
// softmax over 16 KV tiles of 64. scores = QK^T/8 + 0.5*adj[n,m].
// Q/K/V layout [B*N, D] (head h at column h*64). 68-float LDS stride.
// S-phase key mapping kr = tx + 16*j so K-row ds_read_b128 is conflict-free.
// ---------------------------------------------------------------------------
__global__ __launch_bounds__(256)
void attn_kernel(const float* __restrict__ Q, const float* __restrict__ K,
                 const float* __restrict__ V, const float* __restrict__ adj,
                 float* __restrict__ Out) {
  const int bh = blockIdx.y;            // 0..127
  const int b = bh >> 3, h = bh & 7;
  const int n0 = blockIdx.x << 6;
  const int t = threadIdx.x;
  const int tx = t & 15, ty = t >> 4;
  const size_t base = (size_t)b * N_ * D_ + (size_t)h * HD_;
  const float* Qb = Q + base;
  const float* Kb = K + base;
  const float* Vb = V + base;

  __shared__ __align__(16) float Qs[64][68];
  __shared__ __align__(16) float Ks[64][68];
  __shared__ __align__(16) float Vs[64][68];
  __shared__ __align__(16) float Ps[64][68];

  const int lr  = t >> 2;               // 0..63
  const int lc0 = (t & 3) << 4;         // {0,16,32,48}
#pragma unroll
  for (int u = 0; u < 4; ++u)
    *(float4*)(&Qs[lr][lc0 + (u << 2)]) =
        *(const float4*)(Qb + (size_t)(n0 + lr) * D_ + lc0 + (u << 2));

  float om[4], ol[4], o[4][4];
#pragma unroll
  for (int i = 0; i < 4; ++i) {
    om[i] = -INFINITY; ol[i] = 0.f;
#pragma unroll
    for (int j = 0; j < 4; ++j) o[i][j] = 0.f;
  }

  for (int kt = 0; kt < N_ / 64; ++kt) {
    const int kv0 = kt << 6;
    __syncthreads();                    // prev iteration's Ps/Vs reads done
#pragma unroll
    for (int u = 0; u < 4; ++u) {
      *(float4*)(&Ks[lr][lc0 + (u << 2)]) =
          *(const float4*)(Kb + (size_t)(kv0 + lr) * D_ + lc0 + (u << 2));
      *(float4*)(&Vs[lr][lc0 + (u << 2)]) =
          *(const float4*)(Vb + (size_t)(kv0 + lr) * D_ + lc0 + (u << 2));
    }
    __syncthreads();

    float s[4][4] = {};
#pragma unroll
    for (int kk = 0; kk < 16; ++kk) {
      float4 qa[4], kb[4];
#pragma unroll
      for (int i = 0; i < 4; ++i) qa[i] = *(const float4*)(&Qs[(ty << 2) + i][kk << 2]);
#pragma unroll
      for (int j = 0; j < 4; ++j) kb[j] = *(const float4*)(&Ks[tx + (j << 4)][kk << 2]);
#pragma unroll
      for (int i = 0; i < 4; ++i) {
        const float4 q4 = qa[i];
#pragma unroll
        for (int j = 0; j < 4; ++j) {
          const float4 k4 = kb[j];
          s[i][j] += q4.x * k4.x + q4.y * k4.y + q4.z * k4.z + q4.w * k4.w;
        }
      }
    }
#pragma unroll
    for (int i = 0; i < 4; ++i) {
      const float* arow = adj + (size_t)(n0 + (ty << 2) + i) * N_ + kv0 + tx;
      float tm = -INFINITY;
#pragma unroll
      for (int j = 0; j < 4; ++j) {
        s[i][j] = s[i][j] * 0.125f + 0.5f * arow[j << 4];
        tm = fmaxf(tm, s[i][j]);
      }
#pragma unroll
      for (int off = 1; off < 16; off <<= 1) tm = fmaxf(tm, __shfl_xor(tm, off));
      const float nm = fmaxf(om[i], tm);
      const float alpha = __expf(om[i] - nm);   // exp(-inf)=0 on first tile
      float rs = 0.f;
#pragma unroll
      for (int j = 0; j < 4; ++j) { s[i][j] = __expf(s[i][j] - nm); rs += s[i][j]; }
#pragma unroll
      for (int off = 1; off < 16; off <<= 1) rs += __shfl_xor(rs, off);
      ol[i] = ol[i] * alpha + rs;
      om[i] = nm;
#pragma unroll
      for (int j = 0; j < 4; ++j) o[i][j] *= alpha;
    }
#pragma unroll
    for (int i = 0; i < 4; ++i)
#pragma unroll
      for (int j = 0; j < 4; ++j)
        Ps[(ty << 2) + i][tx + (j << 4)] = s[i][j];
    __syncthreads();

#pragma unroll
    for (int kk = 0; kk < 16; ++kk) {
      float4 pa[4], vb[4];
#pragma unroll
      for (int i = 0; i < 4; ++i) pa[i] = *(const float4*)(&Ps[(ty << 2) + i][kk << 2]);
#pragma unroll
      for (int u = 0; u < 4; ++u) vb[u] = *(const float4*)(&Vs[(kk << 2) + u][tx << 2]);
#pragma unroll
      for (int i = 0; i < 4; ++i) {
        const float4 p4 = pa[i];
        o[i][0] += p4.x * vb[0].x + p4.y * vb[1].x + p4.z * vb[2].x + p4.w * vb[3].x;
        o[i][1] += p4.x * vb[0].y + p4.y * vb[1].y + p4.z * vb[2].y + p4.w * vb[3].y;
        o[i][2] += p4.x * vb[0].z + p4.y * vb[1].z + p4.z * vb[2].z + p4.w * vb[3].z;
        o[i][3] += p4.x * vb[0].w + p4.y * vb[1].w + p4.z * vb[2].w + p4.w * vb[3].w;
      }
    }
  }
#pragma unroll
  for (int i = 0; i < 4; ++i) {
    const float inv = 1.f / ol[i];
    float4 r;
    r.x = o[i][0] * inv; r.y = o[i][1] * inv;
    r.z = o[i][2] * inv; r.w = o[i][3] * inv;
    *(float4*)(Out + (size_t)(b * N_ + n0 + (ty << 2) + i) * D_ + h * HD_ + (tx << 2)) = r;
  }
}

// ---------------------------------------------------------------------------
// Kernel 3: in-place residual + LayerNorm. One wave per 512-float row.
// ---------------------------------------------------------------------------
__global__ __launch_bounds__(256)
void ln_kernel(float* __restrict__ Y, const float* __restrict__ Xr,
               const float* __restrict__ g, const float* __restrict__ bta) {
  const int row  = (blockIdx.x << 2) + (threadIdx.x >> 6);
  const int lane = threadIdx.x & 63;
  float* yrow = Y + (size_t)row * D_;
  const float* xrow = Xr + (size_t)row * D_;
  const int c0 = lane << 3;

  const float4 y0 = *(const float4*)(yrow + c0);
  const float4 y1 = *(const float4*)(yrow + c0 + 4);
  const float4 r0 = *(const float4*)(xrow + c0);
  const float4 r1 = *(const float4*)(xrow + c0 + 4);
  float x[8] = {y0.x + r0.x, y0.y + r0.y, y0.z + r0.z, y0.w + r0.w,
                y1.x + r1.x, y1.y + r1.y, y1.z + r1.z, y1.w + r1.w};

  float sum = 0.f;
#pragma unroll
  for (int u = 0; u < 8; ++u) sum += x[u];
#pragma unroll
  for (int off = 32; off >= 1; off >>= 1) sum += __shfl_xor(sum, off);
  const float mu = sum * (1.f / D_);

  float vs = 0.f;
#pragma unroll
  for (int u = 0; u < 8; ++u) { const float d = x[u] - mu; vs += d * d; }
#pragma unroll
  for (int off = 32; off >= 1; off >>= 1) vs += __shfl_xor(vs, off);
  const float var = vs * (1.f / D_) + 1e-5f;
  float rinv = rsqrtf(var);
  rinv = rinv * (1.5f - 0.5f * var * rinv * rinv);   // Newton refine

  const float4 g0 = *(const float4*)(g + c0);
  const float4 g1 = *(const float4*)(g + c0 + 4);
  const float4 b0 = *(const float4*)(bta + c0);
  const float4 b1 = *(const float4*)(bta + c0 + 4);
  float4 o0, o1;
  o0.x = (x[0] - mu) * rinv * g0.x + b0.x;
  o0.y = (x[1] - mu) * rinv * g0.y + b0.y;
  o0.z = (x[2] - mu) * rinv * g0.z + b0.z;
  o0.w = (x[3] - mu) * rinv * g0.w + b0.w;
  o1.x = (x[4] - mu) * rinv * g1.x + b1.x;
  o1.y = (x[5] - mu) * rinv * g1.y + b1.y;
  o1.z = (x[6] - mu) * rinv * g1.z + b1.z;
  o1.w = (x[7] - mu) * rinv * g1.w + b1.w;
  *(float4*)(yrow + c0) = o0;
  *(float4*)(yrow + c0 + 4) = o1;
}

extern "C" void kernel_launch(void* const* d_in, const int* in_sizes, int n_in,
                              void* d_out, int out_size, void* d_ws, size_t ws_size,
                              hipStream_t stream) {
  const float* cur = (const float*)d_in[0];
  const float* lf  = (const float*)d_in[1];
  const float* lw  = (const float*)d_in[2];
  const float* Wq  = (const float*)d_in[3];
  const float* bq  = (const float*)d_in[4];
  const float* Wk  = (const float*)d_in[5];
  const float* bk  = (const float*)d_in[6];
  const float* Wv  = (const float*)d_in[7];
  const float* bv  = (const float*)d_in[8];
  const float* Wo  = (const float*)d_in[9];
  const float* bo  = (const float*)d_in[10];
  const float* adj = (const float*)d_in[11];
  const float* lng = (const float*)d_in[12];
  const float* lnb = (const float*)d_in[13];
  float* out = (float*)d_out;

  float* ws   = (float*)d_ws;
  float* lagg = ws;                              // reused as attn_out later
  float* Qb   = ws + (size_t)1 * BN_ * D_;
  float* Kb   = ws + (size_t)2 * BN_ * D_;
  float* Vb   = ws + (size_t)3 * BN_ * D_;
  float* attn_out = lagg;                        // safe: K/V GEMMs precede attn

  lag_agg_kernel<<<BN_ * D_ / 4 / 256, 256, 0, stream>>>(lf, lw, lagg);
  const dim3 ggrid(D_ / 64, BN_ / 64);
  gemm_xwt_kernel<<<ggrid, 256, 0, stream>>>(cur,  Wq, bq, Qb);
  gemm_xwt_kernel<<<ggrid, 256, 0, stream>>>(lagg, Wk, bk, Kb);
  gemm_xwt_kernel<<<ggrid, 256, 0, stream>>>(lagg, Wv, bv, Vb);
  attn_kernel<<<dim3(N_ / 64, B_ * H_), 256, 0, stream>>>(Qb, Kb, Vb, adj, attn_out);
  gemm_xwt_kernel<<<ggrid, 256, 0, stream>>>(attn_out, Wo, bo, out);
  ln_kernel<<<BN_ / 4, 256, 0, stream>>>(out, cur, lng, lnb);
}

// Round 2
// 573.418 us; speedup vs baseline: 3.4069x; 3.4069x over previous
//
#include <hip/hip_runtime.h>
#include <math.h>

#define B_  16
#define N_  1024
#define L_  7
#define D_  512
#define H_  8
#define HD_ 64
#define BN_ (B_ * N_)

typedef __attribute__((ext_vector_type(4))) float f32x4;
typedef __attribute__((ext_vector_type(8))) short bf16x8;

__device__ __forceinline__ unsigned short f2bf(float f) {
  unsigned int u = __float_as_uint(f);
  u += 0x7fffu + ((u >> 16) & 1u);
  return (unsigned short)(u >> 16);
}
__device__ __forceinline__ unsigned int pack2(float lo, float hi) {
  return (unsigned int)f2bf(lo) | ((unsigned int)f2bf(hi) << 16);
}
__device__ __forceinline__ void load_lds16(const unsigned short* g, unsigned short* s) {
  __builtin_amdgcn_global_load_lds(
      (const __attribute__((address_space(1))) void*)g,
      (__attribute__((address_space(3))) void*)s, 16, 0, 0);
}

// ---------------------------------------------------------------------------
// f32 -> bf16 cast, 8 elems/thread
// ---------------------------------------------------------------------------
__global__ __launch_bounds__(256)
void cast_bf16_kernel(const float* __restrict__ src, unsigned short* __restrict__ dst,
                      int n8) {
  const int i = blockIdx.x * 256 + threadIdx.x;
  if (i >= n8) return;
  const float4 a = ((const float4*)src)[2 * i];
  const float4 b = ((const float4*)src)[2 * i + 1];
  uint4 o;
  o.x = pack2(a.x, a.y); o.y = pack2(a.z, a.w);
  o.z = pack2(b.x, b.y); o.w = pack2(b.z, b.w);
  ((uint4*)dst)[i] = o;
}

// ---------------------------------------------------------------------------
// lag softmax + aggregation, bf16 output. 8 elems/thread.
// ---------------------------------------------------------------------------
__global__ __launch_bounds__(256)
void lag_agg_bf16_kernel(const float* __restrict__ lf, const float* __restrict__ lw,
                         unsigned short* __restrict__ out) {
  const int i = blockIdx.x * 256 + threadIdx.x;   // over BN_*D_/8
  float wv[L_];
  float m = -INFINITY;
#pragma unroll
  for (int l = 0; l < L_; ++l) { wv[l] = lw[l]; m = fmaxf(m, wv[l]); }
  float s = 0.f;
#pragma unroll
  for (int l = 0; l < L_; ++l) { wv[l] = __expf(wv[l] - m); s += wv[l]; }
  const float inv = 1.f / s;

  const int d8 = i & (D_ / 8 - 1);
  const int bn = i >> 6;
  const float* src = lf + (size_t)bn * (L_ * D_) + d8 * 8;
  float acc[8] = {};
#pragma unroll
  for (int l = 0; l < L_; ++l) {
    const float4 v0 = *(const float4*)(src + l * D_);
    const float4 v1 = *(const float4*)(src + l * D_ + 4);
    const float wl = wv[l] * inv;
    acc[0] += v0.x * wl; acc[1] += v0.y * wl; acc[2] += v0.z * wl; acc[3] += v0.w * wl;
    acc[4] += v1.x * wl; acc[5] += v1.y * wl; acc[6] += v1.z * wl; acc[7] += v1.w * wl;
  }
  uint4 o;
  o.x = pack2(acc[0], acc[1]); o.y = pack2(acc[2], acc[3]);
  o.z = pack2(acc[4], acc[5]); o.w = pack2(acc[6], acc[7]);
  ((uint4*)out)[i] = o;
}

// ---------------------------------------------------------------------------
// bf16 MFMA GEMM: C[M,512] = A[M,512] @ W[512,512]^T + bias
// 128x128 tile, BK=64, 4 waves (2x2), wave tile 64x64, 16x16x32 MFMA.
// LDS: row-major [128][64] bf16, chunk-XOR swizzle (c ^= row&7) for
// conflict-free ds_read_b128; staged via global_load_lds w/ inverse-swizzled
// per-lane global source (m173 pattern).
// MODE 0: bf16 row-major out. MODE 1: bf16 V^T out [(b*8+h)*64+d][1024].
// MODE 2: f32 row-major out.
// ---------------------------------------------------------------------------
template<int MODE>
__global__ __launch_bounds__(256)
void gemm_bf16_kernel(const unsigned short* __restrict__ A,
                      const unsigned short* __restrict__ W,
                      const float* __restrict__ bias,
                      void* __restrict__ Cout) {
  __shared__ unsigned short As[128 * 64];
  __shared__ unsigned short Bs[128 * 64];
  const int t = threadIdx.x;
  const int w = t >> 6, l = t & 63;
  const int wm = w >> 1, wn = w & 1;
  const int lc = l & 15, lg = l >> 4;
  const int m0 = blockIdx.y << 7, n0 = blockIdx.x << 7;
  const int srow = l >> 3, sc = l & 7;

  f32x4 acc[4][4];
#pragma unroll
  for (int i = 0; i < 4; ++i)
#pragma unroll
    for (int j = 0; j < 4; ++j)
#pragma unroll
      for (int e = 0; e < 4; ++e) acc[i][j][e] = 0.f;

  for (int k0 = 0; k0 < D_; k0 += 64) {
    __syncthreads();                       // prev iter LDS reads done
#pragma unroll
    for (int i = 0; i < 4; ++i) {
      const int rb = (w << 5) + (i << 3);
      const int row = rb + srow;
      const int c = sc ^ (row & 7);
      load_lds16(A + (size_t)(m0 + row) * D_ + k0 + (c << 3), As + rb * 64);
      load_lds16(W + (size_t)(n0 + row) * D_ + k0 + (c << 3), Bs + rb * 64);
    }
    __syncthreads();                       // drains vmcnt
#pragma unroll
    for (int kb = 0; kb < 2; ++kb) {
      bf16x8 af[4], bfr[4];
#pragma unroll
      for (int mi = 0; mi < 4; ++mi) {
        const int row = (wm << 6) + (mi << 4) + lc;
        const int pos = ((kb << 2) + lg) ^ (row & 7);
        af[mi] = *(const bf16x8*)(As + row * 64 + (pos << 3));
      }
#pragma unroll
      for (int ni = 0; ni < 4; ++ni) {
        const int row = (wn << 6) + (ni << 4) + lc;
        const int pos = ((kb << 2) + lg) ^ (row & 7);
        bfr[ni] = *(const bf16x8*)(Bs + row * 64 + (pos << 3));
      }
#pragma unroll
      for (int mi = 0; mi < 4; ++mi)
#pragma unroll
        for (int ni = 0; ni < 4; ++ni)
          acc[mi][ni] = __builtin_amdgcn_mfma_f32_16x16x32_bf16(
              af[mi], bfr[ni], acc[mi][ni], 0, 0, 0);
    }
  }
  // epilogue: D element (m,n): lane col n = lc, rows m = 4*lg + e
#pragma unroll
  for (int ni = 0; ni < 4; ++ni) {
    const int n = n0 + (wn << 6) + (ni << 4) + lc;
    const float bv = bias[n];
#pragma unroll
    for (int mi = 0; mi < 4; ++mi) {
      const int mb = m0 + (wm << 6) + (mi << 4) + (lg << 2);
      if (MODE == 2) {
        float* O = (float*)Cout;
#pragma unroll
        for (int e = 0; e < 4; ++e)
          O[(size_t)(mb + e) * D_ + n] = acc[mi][ni][e] + bv;
      } else if (MODE == 0) {
        unsigned short* O = (unsigned short*)Cout;
#pragma unroll
        for (int e = 0; e < 4; ++e)
          O[(size_t)(mb + e) * D_ + n] = f2bf(acc[mi][ni][e] + bv);
      } else {  // V^T: Vt[(b*8+h)*64 + d][token]
        unsigned short* O = (unsigned short*)Cout;
        const int bb = mb >> 10, hh = n >> 6, d = n & 63;
        uint2 pk;
        pk.x = pack2(acc[mi][ni][0] + bv, acc[mi][ni][1] + bv);
        pk.y = pack2(acc[mi][ni][2] + bv, acc[mi][ni][3] + bv);
        *(uint2*)(O + ((size_t)((bb << 3) + hh) * HD_ + d) * N_ + (mb & 1023)) = pk;
      }
    }
  }
}

// ---------------------------------------------------------------------------
// bf16 MFMA flash attention per (b,h). Q-tile 64 (wave w owns q = 16w+lc),
// KV-tile 64. Swapped S^T = mfma(K, Q) so each lane holds one full q-row of
// P in registers (16 kv-vals) -> lane-local softmax + 2 shfl_xor. PV computes
// O^T[d][q] with A = V^T (from pre-transposed Vt) and B = P assembled from
// registers via 8 shfl per k-step. No P LDS round-trip. LDS 24 KB.
// ---------------------------------------------------------------------------
__global__ __launch_bounds__(256)
void attn_bf16_kernel(const unsigned short* __restrict__ Q,
                      const unsigned short* __restrict__ K,
                      const unsigned short* __restrict__ Vt,
                      const float* __restrict__ adj,
                      unsigned short* __restrict__ Out) {
  const int bh = blockIdx.y, b = bh >> 3, h = bh & 7;
  const int q0 = blockIdx.x << 6;
  const int t = threadIdx.x, w = t >> 6, l = t & 63;
  const int lc = l & 15, lg = l >> 4;
  __shared__ unsigned short Qs[64 * 64];
  __shared__ unsigned short Ks[64 * 64];
  __shared__ unsigned short Vs[64 * 64];
  const unsigned short* Qg = Q + (size_t)b * N_ * D_ + h * HD_;
  const unsigned short* Kg = K + (size_t)b * N_ * D_ + h * HD_;
  const unsigned short* Vg = Vt + (size_t)((b << 3) + h) * HD_ * N_;

#pragma unroll
  for (int i = 0; i < 2; ++i) {           // stage Q once
    const int rb = (w << 4) + (i << 3);
    const int row = rb + (l >> 3);
    const int c = (l & 7) ^ (row & 7);
    load_lds16(Qg + (size_t)(q0 + row) * D_ + (c << 3), Qs + rb * 64);
  }

  float m_r = -INFINITY, l_r = 0.f;
  f32x4 o[4];
#pragma unroll
  for (int di = 0; di < 4; ++di)
#pragma unroll
    for (int e = 0; e < 4; ++e) o[di][e] = 0.f;
  const int myq = q0 + (w << 4) + lc;

  for (int kt = 0; kt < 16; ++kt) {
    const int kv0 = kt << 6;
#pragma unroll
    for (int i = 0; i < 2; ++i) {         // stage K (row-major) and V^T (d-major)
      const int rb = (w << 4) + (i << 3);
      const int row = rb + (l >> 3);
      const int c = (l & 7) ^ (row & 7);
      load_lds16(Kg + (size_t)(kv0 + row) * D_ + (c << 3), Ks + rb * 64);
      load_lds16(Vg + (size_t)row * N_ + kv0 + (c << 3), Vs + rb * 64);
    }
    f32x4 aj[4];
#pragma unroll
    for (int ni = 0; ni < 4; ++ni)
      aj[ni] = *(const f32x4*)(adj + (size_t)myq * N_ + kv0 + (ni << 4) + (lg << 2));
    __syncthreads();                      // drains vmcnt (staging complete)

    // S^T[kv][q]: frag ni covers kv-rows 16ni..+15; lane holds q=lc, kv=4lg+e
    bf16x8 qf[2];
#pragma unroll
    for (int kb = 0; kb < 2; ++kb) {
      const int row = (w << 4) + lc;
      const int pos = ((kb << 2) + lg) ^ (row & 7);
      qf[kb] = *(const bf16x8*)(Qs + row * 64 + (pos << 3));
    }
    f32x4 st[4];
#pragma unroll
    for (int ni = 0; ni < 4; ++ni)
#pragma unroll
      for (int e = 0; e < 4; ++e) st[ni][e] = 0.f;
#pragma unroll
    for (int ni = 0; ni < 4; ++ni)
#pragma unroll
      for (int kb = 0; kb < 2; ++kb) {
        const int row = (ni << 4) + lc;
        const int pos = ((kb << 2) + lg) ^ (row & 7);
        const bf16x8 kf = *(const bf16x8*)(Ks + row * 64 + (pos << 3));
        st[ni] = __builtin_amdgcn_mfma_f32_16x16x32_bf16(kf, qf[kb], st[ni], 0, 0, 0);
      }

    // online softmax: lane-local over 16 vals + cross-g shfl_xor(16,32)
    float tmax = -INFINITY;
#pragma unroll
    for (int ni = 0; ni < 4; ++ni)
#pragma unroll
      for (int e = 0; e < 4; ++e) {
        const float v = st[ni][e] * 0.125f + 0.5f * aj[ni][e];
        st[ni][e] = v;
        tmax = fmaxf(tmax, v);
      }
    tmax = fmaxf(tmax, __shfl_xor(tmax, 16));
    tmax = fmaxf(tmax, __shfl_xor(tmax, 32));
    const float mnew = fmaxf(m_r, tmax);
    const float alpha = __expf(m_r - mnew);     // exp(-inf)=0 first tile
    float ts = 0.f;
#pragma unroll
    for (int ni = 0; ni < 4; ++ni)
#pragma unroll
      for (int e = 0; e < 4; ++e) {
        const float p = __expf(st[ni][e] - mnew);
        st[ni][e] = p;
        ts += p;
      }
    ts += __shfl_xor(ts, 16);
    ts += __shfl_xor(ts, 32);
    l_r = l_r * alpha + ts;
    m_r = mnew;
#pragma unroll
    for (int di = 0; di < 4; ++di)
#pragma unroll
      for (int e = 0; e < 4; ++e) o[di][e] *= alpha;

    // pack P^T quads: p2[ni][j] = bf16x2 of kv {16ni+4lg+2j, +1} at col q
    unsigned int p2[4][2];
#pragma unroll
    for (int ni = 0; ni < 4; ++ni) {
      p2[ni][0] = pack2(st[ni][0], st[ni][1]);
      p2[ni][1] = pack2(st[ni][2], st[ni][3]);
    }
    // PV: O^T[d][q] += V^T-frag x P-frag. B-frag (kv=32kb+8lg..+7) gathered
    // from lanes (q, 2*(lg&1)) and (q, 2*(lg&1)+1), frag index 2kb+(lg>>1).
    const int sA = lc + ((lg & 1) << 5);
    const int sB = sA + 16;
    const bool hiq = lg >= 2;
#pragma unroll
    for (int kb = 0; kb < 2; ++kb) {
      const unsigned int dA0 = (unsigned int)__shfl((int)p2[2 * kb][0], sA);
      const unsigned int dA1 = (unsigned int)__shfl((int)p2[2 * kb][1], sA);
      const unsigned int dA2 = (unsigned int)__shfl((int)p2[2 * kb][0], sB);
      const unsigned int dA3 = (unsigned int)__shfl((int)p2[2 * kb][1], sB);
      const unsigned int dB0 = (unsigned int)__shfl((int)p2[2 * kb + 1][0], sA);
      const unsigned int dB1 = (unsigned int)__shfl((int)p2[2 * kb + 1][1], sA);
      const unsigned int dB2 = (unsigned int)__shfl((int)p2[2 * kb + 1][0], sB);
      const unsigned int dB3 = (unsigned int)__shfl((int)p2[2 * kb + 1][1], sB);
      union { unsigned int u[4]; bf16x8 v; } pb;
      pb.u[0] = hiq ? dB0 : dA0;
      pb.u[1] = hiq ? dB1 : dA1;
      pb.u[2] = hiq ? dB2 : dA2;
      pb.u[3] = hiq ? dB3 : dA3;
#pragma unroll
      for (int di = 0; di < 4; ++di) {
        const int row = (di << 4) + lc;
        const int pos = ((kb << 2) + lg) ^ (row & 7);
        const bf16x8 vf = *(const bf16x8*)(Vs + row * 64 + (pos << 3));
        o[di] = __builtin_amdgcn_mfma_f32_16x16x32_bf16(vf, pb.v, o[di], 0, 0, 0);
      }
    }
    __syncthreads();                      // before next tile's staging
  }
  // epilogue: lane owns q = myq, d = 16di + 4lg + e
  const float inv = 1.f / l_r;
  unsigned short* Ob = Out + (size_t)(b * N_ + q0 + (w << 4) + lc) * D_ + h * HD_;
#pragma unroll
  for (int di = 0; di < 4; ++di) {
    uint2 pk;
    pk.x = pack2(o[di][0] * inv, o[di][1] * inv);
    pk.y = pack2(o[di][2] * inv, o[di][3] * inv);
    *(uint2*)(Ob + (di << 4) + (lg << 2)) = pk;
  }
}

// ---------------------------------------------------------------------------
// in-place residual + LayerNorm, one wave per 512-float row (f32)
// ---------------------------------------------------------------------------
__global__ __launch_bounds__(256)
void ln_kernel(float* __restrict__ Y, const float* __restrict__ Xr,
               const float* __restrict__ g, const float* __restrict__ bta) {
  const int row  = (blockIdx.x << 2) + (threadIdx.x >> 6);
  const int lane = threadIdx.x & 63;
  float* yrow = Y + (size_t)row * D_;
  const float* xrow = Xr + (size_t)row * D_;
  const int c0 = lane << 3;

  const float4 y0 = *(const float4*)(yrow + c0);
  const float4 y1 = *(const float4*)(yrow + c0 + 4);
  const float4 r0 = *(const float4*)(xrow + c0);
  const float4 r1 = *(const float4*)(xrow + c0 + 4);
  float x[8] = {y0.x + r0.x, y0.y + r0.y, y0.z + r0.z, y0.w + r0.w,
                y1.x + r1.x, y1.y + r1.y, y1.z + r1.z, y1.w + r1.w};

  float sum = 0.f;
#pragma unroll
  for (int u = 0; u < 8; ++u) sum += x[u];
#pragma unroll
  for (int off = 32; off >= 1; off >>= 1) sum += __shfl_xor(sum, off);
  const float mu = sum * (1.f / D_);

  float vs = 0.f;
#pragma unroll
  for (int u = 0; u < 8; ++u) { const float d = x[u] - mu; vs += d * d; }
#pragma unroll
  for (int off = 32; off >= 1; off >>= 1) vs += __shfl_xor(vs, off);
  const float var = vs * (1.f / D_) + 1e-5f;
  float rinv = rsqrtf(var);
  rinv = rinv * (1.5f - 0.5f * var * rinv * rinv);   // Newton refine

  const float4 g0 = *(const float4*)(g + c0);
  const float4 g1 = *(const float4*)(g + c0 + 4);
  const float4 b0 = *(const float4*)(bta + c0);
  const float4 b1 = *(const float4*)(bta + c0 + 4);
  float4 o0, o1;
  o0.x = (x[0] - mu) * rinv * g0.x + b0.x;
  o0.y = (x[1] - mu) * rinv * g0.y + b0.y;
  o0.z = (x[2] - mu) * rinv * g0.z + b0.z;
  o0.w = (x[3] - mu) * rinv * g0.w + b0.w;
  o1.x = (x[4] - mu) * rinv * g1.x + b1.x;
  o1.y = (x[5] - mu) * rinv * g1.y + b1.y;
  o1.z = (x[6] - mu) * rinv * g1.z + b1.z;
  o1.w = (x[7] - mu) * rinv * g1.w + b1.w;
  *(float4*)(yrow + c0) = o0;
  *(float4*)(yrow + c0 + 4) = o1;
}

extern "C" void kernel_launch(void* const* d_in, const int* in_sizes, int n_in,
                              void* d_out, int out_size, void* d_ws, size_t ws_size,
                              hipStream_t stream) {
  const float* cur = (const float*)d_in[0];
  const float* lf  = (const float*)d_in[1];
  const float* lw  = (const float*)d_in[2];
  const float* Wq  = (const float*)d_in[3];
  const float* bq  = (const float*)d_in[4];
  const float* Wk  = (const float*)d_in[5];
  const float* bk  = (const float*)d_in[6];
  const float* Wv  = (const float*)d_in[7];
  const float* bv  = (const float*)d_in[8];
  const float* Wo  = (const float*)d_in[9];
  const float* bo  = (const float*)d_in[10];
  const float* adj = (const float*)d_in[11];
  const float* lng = (const float*)d_in[12];
  const float* lnb = (const float*)d_in[13];
  float* out = (float*)d_out;

  const size_t NE = (size_t)BN_ * D_;   // 8388608 elements
  unsigned short* wsb   = (unsigned short*)d_ws;
  unsigned short* curb  = wsb;
  unsigned short* laggb = wsb + NE;
  unsigned short* Qb    = wsb + 2 * NE;
  unsigned short* Kb    = wsb + 3 * NE;
  unsigned short* Vtb   = wsb + 4 * NE;
  unsigned short* attnb = wsb + 5 * NE;
  unsigned short* Wqb   = wsb + 6 * NE;
  unsigned short* Wkb   = Wqb + (size_t)D_ * D_;
  unsigned short* Wvb   = Wkb + (size_t)D_ * D_;
  unsigned short* Wob   = Wvb + (size_t)D_ * D_;
  // total: 6*16.8 MB + 4*0.5 MB = ~103 MB < ws (>=134 MB per R1 usage)

  cast_bf16_kernel<<<BN_ * D_ / 8 / 256, 256, 0, stream>>>(cur, curb, BN_ * D_ / 8);
  cast_bf16_kernel<<<D_ * D_ / 8 / 256, 256, 0, stream>>>(Wq, Wqb, D_ * D_ / 8);
  cast_bf16_kernel<<<D_ * D_ / 8 / 256, 256, 0, stream>>>(Wk, Wkb, D_ * D_ / 8);
  cast_bf16_kernel<<<D_ * D_ / 8 / 256, 256, 0, stream>>>(Wv, Wvb, D_ * D_ / 8);
  cast_bf16_kernel<<<D_ * D_ / 8 / 256, 256, 0, stream>>>(Wo, Wob, D_ * D_ / 8);
  lag_agg_bf16_kernel<<<BN_ * D_ / 8 / 256, 256, 0, stream>>>(lf, lw, laggb);

  const dim3 gg(D_ / 128, BN_ / 128);   // (4, 128)
  gemm_bf16_kernel<0><<<gg, 256, 0, stream>>>(curb,  Wqb, bq, (void*)Qb);
  gemm_bf16_kernel<0><<<gg, 256, 0, stream>>>(laggb, Wkb, bk, (void*)Kb);
  gemm_bf16_kernel<1><<<gg, 256, 0, stream>>>(laggb, Wvb, bv, (void*)Vtb);
  attn_bf16_kernel<<<dim3(N_ / 64, B_ * H_), 256, 0, stream>>>(Qb, Kb, Vtb, adj, attnb);
  gemm_bf16_kernel<2><<<gg, 256, 0, stream>>>(attnb, Wob, bo, (void*)out);
  ln_kernel<<<BN_ / 4, 256, 0, stream>>>(out, cur, lng, lnb);
}